// Round 5
// baseline (291.860 us; speedup 1.0000x reference)
//
#include <hip/hip_runtime.h>
#include <hip/hip_bf16.h>

// LVQ: out[n] = classes[argmin_k ||x_n - c_k||^2]
// N=65536, D=512, K=1024, classes int32.
//
// score[n][k] = csq[k] - 2 * x_n . c_k   (x_sq dropped: row-constant)
// cross via 3-pass bf16-split MFMA (xh*ch + xh*cl + xl*ch), fp32 accum.
// Round 5: 32x32x16 MFMA (half the instruction count, 15% faster pipe),
// 1 barrier + 1 vmcnt per K-tile (dbuf), 2 setprio-wrapped 24-MFMA clusters.
// Staging/swizzle/epilogue-atomics identical to verified r2-r4 structure.

#define N_ROWS 65536
#define DIM    512
#define K_CB   1024
#define NT     16          // DIM / BK, BK=32
#define LDSBUF 32768       // elements per buffer: 4 arrays x 8192 (16KB each)

typedef short bf16x8  __attribute__((ext_vector_type(8)));
typedef float f32x4   __attribute__((ext_vector_type(4)));
typedef float f32x16  __attribute__((ext_vector_type(16)));

__device__ __forceinline__ unsigned short f2bf_rn(float f) {
    unsigned u = __float_as_uint(f);
    unsigned r = (u + 0x7FFFu + ((u >> 16) & 1u)) >> 16;
    return (unsigned short)r;
}
__device__ __forceinline__ float bf2f(unsigned short h) {
    return __uint_as_float(((unsigned)h) << 16);
}

__device__ __forceinline__ void gload16(const void* g, void* l) {
    __builtin_amdgcn_global_load_lds(
        (const __attribute__((address_space(1))) unsigned int*)g,
        (__attribute__((address_space(3))) unsigned int*)l, 16, 0, 0);
}

// ---------------- init: packed per-row (min,argmin) to +inf ----------------
__global__ void init_kernel(unsigned long long* __restrict__ packed) {
    int n = blockIdx.x * 256 + threadIdx.x;
    if (n < N_ROWS) packed[n] = ~0ull;
}

// ---------------- csq[k] = sum_d C[k][d]^2 (fp32) ----------------
__global__ void csq_kernel(const float* __restrict__ C, float* __restrict__ csq) {
    int wid  = (blockIdx.x * blockDim.x + threadIdx.x) >> 6;   // one wave per k
    int lane = threadIdx.x & 63;
    const float4* p = (const float4*)(C + (size_t)wid * DIM);
    float4 a = p[lane * 2];
    float4 b = p[lane * 2 + 1];
    float s = a.x*a.x + a.y*a.y + a.z*a.z + a.w*a.w
            + b.x*b.x + b.y*b.y + b.z*b.z + b.w*b.w;
    #pragma unroll
    for (int m = 1; m < 64; m <<= 1) s += __shfl_xor(s, m, 64);
    if (lane == 0) csq[wid] = s;
}

// ---------------- one-shot fp32 -> bf16 hi/lo split ----------------
__global__ void split_kernel(const float* __restrict__ src,
                             unsigned short* __restrict__ h,
                             unsigned short* __restrict__ l, int n4) {
    int stride = gridDim.x * 256;
    for (int i = blockIdx.x * 256 + threadIdx.x; i < n4; i += stride) {
        float4 v = ((const float4*)src)[i];
        ushort4 hh, ll;
        float f;
        f = v.x; hh.x = f2bf_rn(f); ll.x = f2bf_rn(f - bf2f(hh.x));
        f = v.y; hh.y = f2bf_rn(f); ll.y = f2bf_rn(f - bf2f(hh.y));
        f = v.z; hh.z = f2bf_rn(f); ll.z = f2bf_rn(f - bf2f(hh.z));
        f = v.w; hh.w = f2bf_rn(f); ll.w = f2bf_rn(f - bf2f(hh.w));
        ((ushort4*)h)[i] = hh;
        ((ushort4*)l)[i] = ll;
    }
}

// ---------------- fused GEMM + argmin, 32x32x16 MFMA ----------------
// LDS tile element layout per array: [row 0..255][group 0..3][8 elems],
// linear idx = row*32 + g*8. LDS[row][g] holds GLOBAL k-group g^((row>>1)&3)
// (swizzle applied on the per-lane global source address; linear LDS dest as
// global_load_lds requires). Fragment reads use the same XOR.
// MFMA 32x32x16 layouts: A/B lane l: row/col = l&31, k = (l>>5)*8 + j.
// C/D (HW-verified m74/m101): col = l&31, row = (r&3)+8*(r>>2)+4*(l>>5).
__global__ __launch_bounds__(512, 2)
void gemm_argmin(const unsigned short* __restrict__ Xh,
                 const unsigned short* __restrict__ Xl,
                 const unsigned short* __restrict__ Ch,
                 const unsigned short* __restrict__ Cl,
                 const float* __restrict__ csq,
                 unsigned long long* __restrict__ packed) {
    extern __shared__ unsigned short smem[];   // 2 * LDSBUF elements (128 KB)

    // XCD-aware mapping: the 4 col-tiles of one row-tile run concurrently
    // on one XCD -> X tile (512 KB) fetched into that L2 once.
    int b  = blockIdx.x;
    int x  = b & 7;
    int m8 = b >> 3;                   // 0..127
    int rowtile = x * 32 + (m8 >> 2);  // 0..255
    int coltile = m8 & 3;              // 0..3
    int n0 = rowtile * 256;
    int k0 = coltile * 256;

    int tid  = threadIdx.x;
    int w    = tid >> 6;
    int lane = tid & 63;
    int wr   = w >> 2, wc = w & 3;     // 2M x 4N waves; wave tile 128x64
    int rbase = wr * 128, cbase = wc * 64;
    int l31  = lane & 31;
    int gsel = lane >> 5;              // k-group half within MFMA
    int swz  = (lane >> 1) & 3;        // = ((row&31)>>1)&3 for our row patterns
    int g0off = ((gsel)     ^ swz) * 8;   // k-step 0 group byte-elem offset
    int g1off = ((2 + gsel) ^ swz) * 8;   // k-step 1

    // staging mapping: thread -> (row = c*128 + (tid>>2), group = tid&3)
    int srow = tid >> 2;
    int sgrp = tid & 3;
    int w512 = w * 512;                // wave-uniform part of tid*8

    f32x16 acc[4][2];                  // [m 32-row block][n 32-col block]
    #pragma unroll
    for (int i = 0; i < 4; i++)
        #pragma unroll
        for (int j = 0; j < 2; j++)
            acc[i][j] = (f32x16){0.f};

    // issue 4 staging chunks (half c) for K-tile t into buf[t&1]
    auto issue_half = [&](int t, int c) {
        int d0 = t * 32;
        unsigned short* bufn = smem + (t & 1) * LDSBUF;
        int r  = c * 128 + srow;
        int gg = sgrp ^ ((r >> 1) & 3);
        size_t oX = (size_t)(n0 + r) * DIM + d0 + gg * 8;
        size_t oC = (size_t)(k0 + r) * DIM + d0 + gg * 8;
        int dl = c * 4096 + w512;             // + lane*8 added by HW
        gload16(Xh + oX, bufn + dl);
        gload16(Xl + oX, bufn + 8192 + dl);
        gload16(Ch + oC, bufn + 16384 + dl);
        gload16(Cl + oC, bufn + 24576 + dl);
    };

    issue_half(0, 0);
    issue_half(0, 1);
    asm volatile("s_waitcnt vmcnt(0)" ::: "memory");
    __builtin_amdgcn_s_barrier();
    asm volatile("" ::: "memory");

    for (int t = 0; t < NT; ++t) {
        const unsigned short* buf = smem + (t & 1) * LDSBUF;
        const unsigned short* pA = buf + (rbase + l31) * 32;
        const unsigned short* pB = buf + 16384 + (cbase + l31) * 32;

        // ---- k-step 0: reads, prefetch-issue, 24 MFMA ----
        bf16x8 ah[4], al[4], bh[2], bl[2];
        #pragma unroll
        for (int m = 0; m < 4; m++) {
            ah[m] = *(const bf16x8*)(pA + m * 1024 + g0off);
            al[m] = *(const bf16x8*)(pA + 8192 + m * 1024 + g0off);
        }
        #pragma unroll
        for (int n = 0; n < 2; n++) {
            bh[n] = *(const bf16x8*)(pB + n * 1024 + g0off);
            bl[n] = *(const bf16x8*)(pB + 8192 + n * 1024 + g0off);
        }
        if (t + 1 < NT) issue_half(t + 1, 0);

        __builtin_amdgcn_s_setprio(1);
        // pass-major: 8 independent MFMAs between dependent acc reuses
        #pragma unroll
        for (int m = 0; m < 4; m++)
            #pragma unroll
            for (int n = 0; n < 2; n++)
                acc[m][n] = __builtin_amdgcn_mfma_f32_32x32x16_bf16(ah[m], bh[n], acc[m][n], 0, 0, 0);
        #pragma unroll
        for (int m = 0; m < 4; m++)
            #pragma unroll
            for (int n = 0; n < 2; n++)
                acc[m][n] = __builtin_amdgcn_mfma_f32_32x32x16_bf16(ah[m], bl[n], acc[m][n], 0, 0, 0);
        #pragma unroll
        for (int m = 0; m < 4; m++)
            #pragma unroll
            for (int n = 0; n < 2; n++)
                acc[m][n] = __builtin_amdgcn_mfma_f32_32x32x16_bf16(al[m], bh[n], acc[m][n], 0, 0, 0);
        __builtin_amdgcn_s_setprio(0);

        // ---- k-step 1: reads, prefetch-issue, 24 MFMA ----
        bf16x8 ah1[4], al1[4], bh1[2], bl1[2];
        #pragma unroll
        for (int m = 0; m < 4; m++) {
            ah1[m] = *(const bf16x8*)(pA + m * 1024 + g1off);
            al1[m] = *(const bf16x8*)(pA + 8192 + m * 1024 + g1off);
        }
        #pragma unroll
        for (int n = 0; n < 2; n++) {
            bh1[n] = *(const bf16x8*)(pB + n * 1024 + g1off);
            bl1[n] = *(const bf16x8*)(pB + 8192 + n * 1024 + g1off);
        }
        if (t + 1 < NT) issue_half(t + 1, 1);

        __builtin_amdgcn_s_setprio(1);
        #pragma unroll
        for (int m = 0; m < 4; m++)
            #pragma unroll
            for (int n = 0; n < 2; n++)
                acc[m][n] = __builtin_amdgcn_mfma_f32_32x32x16_bf16(ah1[m], bh1[n], acc[m][n], 0, 0, 0);
        #pragma unroll
        for (int m = 0; m < 4; m++)
            #pragma unroll
            for (int n = 0; n < 2; n++)
                acc[m][n] = __builtin_amdgcn_mfma_f32_32x32x16_bf16(ah1[m], bl1[n], acc[m][n], 0, 0, 0);
        #pragma unroll
        for (int m = 0; m < 4; m++)
            #pragma unroll
            for (int n = 0; n < 2; n++)
                acc[m][n] = __builtin_amdgcn_mfma_f32_32x32x16_bf16(al1[m], bh1[n], acc[m][n], 0, 0, 0);
        __builtin_amdgcn_s_setprio(0);

        // tile boundary: all waves' gloads for t+1 landed; buf[t&1] free.
        if (t + 1 < NT) {
            asm volatile("s_waitcnt vmcnt(0)" ::: "memory");
            __builtin_amdgcn_s_barrier();
            asm volatile("" ::: "memory");
        }
    }

    // Epilogue: score = csq[col] - 2*cross; per-row packed-min, atomic merge.
    // C/D: col = l31, row = (r&3) + 8*(r>>2) + 4*gsel (within 32-row block).
    float cs2[2];
    #pragma unroll
    for (int n = 0; n < 2; n++) cs2[n] = csq[k0 + cbase + n * 32 + l31];

    #pragma unroll
    for (int m = 0; m < 4; m++) {
        #pragma unroll
        for (int r = 0; r < 16; r++) {
            unsigned long long best = ~0ull;
            #pragma unroll
            for (int n = 0; n < 2; n++) {
                float s = cs2[n] - 2.0f * acc[m][n][r];
                unsigned kb  = __float_as_uint(s);
                unsigned key = kb ^ (unsigned)(((int)kb >> 31) | 0x80000000);
                unsigned col = (unsigned)(k0 + cbase + n * 32 + l31);
                unsigned long long pk = (((unsigned long long)key) << 32) | col;
                best = pk < best ? pk : best;
            }
            // butterfly across the 32 lanes holding this row
            #pragma unroll
            for (int mask = 1; mask <= 16; mask <<= 1) {
                unsigned hi = __shfl_xor((unsigned)(best >> 32), mask, 64);
                unsigned lo = __shfl_xor((unsigned)(best & 0xFFFFFFFFu), mask, 64);
                unsigned long long other = (((unsigned long long)hi) << 32) | lo;
                best = other < best ? other : best;
            }
            if (l31 == 0) {
                int grow = n0 + rbase + m * 32 + (r & 3) + 8 * (r >> 2) + 4 * gsel;
                atomicMin(&packed[grow], best);
            }
        }
    }
}

// ---------------- fallback GEMM (in-kernel conversion, round-1 path) -------
__device__ __forceinline__ void stage_tile_fb(const float* __restrict__ src,
                                              unsigned short* __restrict__ Hh,
                                              unsigned short* __restrict__ Hl,
                                              int t) {
    int rsub = t >> 4;
    int f4i  = t & 15;
    int g    = f4i >> 1;
    int off  = (f4i & 1) * 4;
    #pragma unroll
    for (int p = 0; p < 8; p++) {
        int row = p * 16 + rsub;
        float4 v = *(const float4*)(src + (size_t)row * DIM + f4i * 4);
        ushort4 h, l;
        float f;
        f = v.x; h.x = f2bf_rn(f); l.x = f2bf_rn(f - bf2f(h.x));
        f = v.y; h.y = f2bf_rn(f); l.y = f2bf_rn(f - bf2f(h.y));
        f = v.z; h.z = f2bf_rn(f); l.z = f2bf_rn(f - bf2f(h.z));
        f = v.w; h.w = f2bf_rn(f); l.w = f2bf_rn(f - bf2f(h.w));
        int sg  = g ^ (row & 7);
        int idx = row * 64 + sg * 8 + off;
        *(ushort4*)(Hh + idx) = h;
        *(ushort4*)(Hl + idx) = l;
    }
}

__global__ __launch_bounds__(256, 2)
void gemm_argmin_fb(const float* __restrict__ X, const float* __restrict__ C,
                    const float* __restrict__ csq,
                    unsigned long long* __restrict__ packed) {
    __shared__ unsigned short AhL[128 * 64];
    __shared__ unsigned short AlL[128 * 64];
    __shared__ unsigned short BhL[128 * 64];
    __shared__ unsigned short BlL[128 * 64];

    int b = blockIdx.x;
    int x = b & 7;
    int m8 = b >> 3;
    int rowtile = x * 64 + (m8 >> 3);
    int coltile = m8 & 7;
    int n0 = rowtile * 128;
    int k0 = coltile * 128;

    int t    = threadIdx.x;
    int w    = t >> 6;
    int lane = t & 63;
    int wr   = w >> 1, wc = w & 1;
    int rbase = wr * 64, cbase = wc * 64;
    int lrow = lane & 15;
    int lk   = lane >> 4;

    f32x4 acc[4][4];
    #pragma unroll
    for (int i = 0; i < 4; i++)
        #pragma unroll
        for (int j = 0; j < 4; j++)
            acc[i][j] = (f32x4){0.f, 0.f, 0.f, 0.f};

    for (int d0 = 0; d0 < DIM; d0 += 64) {
        stage_tile_fb(X + (size_t)n0 * DIM + d0, AhL, AlL, t);
        stage_tile_fb(C + (size_t)k0 * DIM + d0, BhL, BlL, t);
        __syncthreads();

        #pragma unroll
        for (int kk = 0; kk < 2; kk++) {
            int gidx = kk * 4 + lk;
            bf16x8 ah[4], al[4], bh[4], bl[4];
            #pragma unroll
            for (int m = 0; m < 4; m++) {
                int row = rbase + m * 16 + lrow;
                int sg  = gidx ^ (row & 7);
                ah[m] = *(const bf16x8*)&AhL[row * 64 + sg * 8];
                al[m] = *(const bf16x8*)&AlL[row * 64 + sg * 8];
            }
            #pragma unroll
            for (int n = 0; n < 4; n++) {
                int col = cbase + n * 16 + lrow;
                int sg  = gidx ^ (col & 7);
                bh[n] = *(const bf16x8*)&BhL[col * 64 + sg * 8];
                bl[n] = *(const bf16x8*)&BlL[col * 64 + sg * 8];
            }
            #pragma unroll
            for (int m = 0; m < 4; m++)
                #pragma unroll
                for (int n = 0; n < 4; n++) {
                    acc[m][n] = __builtin_amdgcn_mfma_f32_16x16x32_bf16(ah[m], bh[n], acc[m][n], 0, 0, 0);
                    acc[m][n] = __builtin_amdgcn_mfma_f32_16x16x32_bf16(ah[m], bl[n], acc[m][n], 0, 0, 0);
                    acc[m][n] = __builtin_amdgcn_mfma_f32_16x16x32_bf16(al[m], bh[n], acc[m][n], 0, 0, 0);
                }
        }
        __syncthreads();
    }

    float cs[4];
    #pragma unroll
    for (int n = 0; n < 4; n++) cs[n] = csq[k0 + cbase + n * 16 + lrow];

    #pragma unroll
    for (int m = 0; m < 4; m++) {
        #pragma unroll
        for (int r = 0; r < 4; r++) {
            unsigned long long best = ~0ull;
            #pragma unroll
            for (int n = 0; n < 4; n++) {
                float s = cs[n] - 2.0f * acc[m][n][r];
                unsigned kb  = __float_as_uint(s);
                unsigned key = kb ^ (unsigned)(((int)kb >> 31) | 0x80000000);
                unsigned col = (unsigned)(k0 + cbase + n * 16 + lrow);
                unsigned long long pk = (((unsigned long long)key) << 32) | col;
                best = pk < best ? pk : best;
            }
            #pragma unroll
            for (int mask = 1; mask <= 8; mask <<= 1) {
                unsigned hi = __shfl_xor((unsigned)(best >> 32), mask, 64);
                unsigned lo = __shfl_xor((unsigned)(best & 0xFFFFFFFFu), mask, 64);
                unsigned long long other = (((unsigned long long)hi) << 32) | lo;
                best = other < best ? other : best;
            }
            if (lrow == 0) {
                int grow = n0 + rbase + m * 16 + lk * 4 + r;
                atomicMin(&packed[grow], best);
            }
        }
    }
}

// ---------------- winner -> class ----------------
__global__ void map_kernel(const unsigned long long* __restrict__ packed,
                           const int* __restrict__ classes,
                           int* __restrict__ out) {
    int n = blockIdx.x * 256 + threadIdx.x;
    if (n < N_ROWS) {
        unsigned col = (unsigned)(packed[n] & 0xFFFFFFFFull);
        out[n] = classes[col];
    }
}

extern "C" void kernel_launch(void* const* d_in, const int* in_sizes, int n_in,
                              void* d_out, int out_size, void* d_ws, size_t ws_size,
                              hipStream_t stream) {
    const float* X       = (const float*)d_in[0];
    const float* C       = (const float*)d_in[1];
    const int*   classes = (const int*)d_in[2];
    int*         out     = (int*)d_out;

    char* ws = (char*)d_ws;
    size_t off = 0;
    unsigned long long* packed = (unsigned long long*)(ws + off); off += (size_t)N_ROWS * 8;
    float* csq = (float*)(ws + off);                              off += (size_t)K_CB * 4;
    unsigned short* Xh = (unsigned short*)(ws + off);             off += (size_t)N_ROWS * DIM * 2;
    unsigned short* Xl = (unsigned short*)(ws + off);             off += (size_t)N_ROWS * DIM * 2;
    unsigned short* Ch = (unsigned short*)(ws + off);             off += (size_t)K_CB * DIM * 2;
    unsigned short* Cl = (unsigned short*)(ws + off);             off += (size_t)K_CB * DIM * 2;

    init_kernel<<<N_ROWS / 256, 256, 0, stream>>>(packed);
    csq_kernel<<<K_CB / 4, 256, 0, stream>>>(C, csq);

    if (ws_size >= off) {
        split_kernel<<<2048, 256, 0, stream>>>(X, Xh, Xl, N_ROWS * DIM / 4);
        split_kernel<<<512, 256, 0, stream>>>(C, Ch, Cl, K_CB * DIM / 4);
        hipFuncSetAttribute((const void*)gemm_argmin,
                            hipFuncAttributeMaxDynamicSharedMemorySize,
                            2 * LDSBUF * sizeof(unsigned short));
        gemm_argmin<<<(N_ROWS / 256) * (K_CB / 256), 512,
                      2 * LDSBUF * sizeof(unsigned short), stream>>>(
            Xh, Xl, Ch, Cl, csq, packed);
    } else {
        gemm_argmin_fb<<<(N_ROWS / 128) * (K_CB / 128), 256, 0, stream>>>(X, C, csq, packed);
    }
    map_kernel<<<N_ROWS / 256, 256, 0, stream>>>(packed, classes, out);
}

// Round 6
// 254.224 us; speedup vs baseline: 1.1480x; 1.1480x over previous
//
#include <hip/hip_runtime.h>
#include <hip/hip_bf16.h>

// LVQ: out[n] = classes[argmin_k ||x_n - c_k||^2]
// N=65536, D=512, K=1024, classes int32.
//
// score[n][k] = csq[k] - 2 * x_n . c_k   (x_sq dropped: row-constant)
// cross via 3-pass bf16-split MFMA (xh*ch + xh*cl + xl*ch), fp32 accum.
// Round 6: back to 16x16x32 (r5's 32x32 broke the swizzle: 1.3e7 conflicts).
// Counted-vmcnt pipeline with need-ordered half-tiles: h1 = A rows
// {0-63,128-191} + all B (what phases 0-1 consume), h2 = A rows
// {64-127,192-255} (phases 2-3). Waits: vmcnt(2) at tile top, vmcnt(6)
// mid-tile -- never 0 in the main loop (T4). 2 barriers/tile (was 5).

#define N_ROWS 65536
#define DIM    512
#define K_CB   1024
#define NT     16          // DIM / BK, BK=32
#define LDSBUF 32768       // elements per buffer: Ah|Al|Bh|Bl = 4 x 8192

typedef short bf16x8 __attribute__((ext_vector_type(8)));
typedef float f32x4  __attribute__((ext_vector_type(4)));

__device__ __forceinline__ unsigned short f2bf_rn(float f) {
    unsigned u = __float_as_uint(f);
    unsigned r = (u + 0x7FFFu + ((u >> 16) & 1u)) >> 16;
    return (unsigned short)r;
}
__device__ __forceinline__ float bf2f(unsigned short h) {
    return __uint_as_float(((unsigned)h) << 16);
}

__device__ __forceinline__ void gload16(const void* g, void* l) {
    __builtin_amdgcn_global_load_lds(
        (const __attribute__((address_space(1))) unsigned int*)g,
        (__attribute__((address_space(3))) unsigned int*)l, 16, 0, 0);
}

// ---------------- init: packed per-row (min,argmin) to +inf ----------------
__global__ void init_kernel(unsigned long long* __restrict__ packed) {
    int n = blockIdx.x * 256 + threadIdx.x;
    if (n < N_ROWS) packed[n] = ~0ull;
}

// ---------------- csq[k] = sum_d C[k][d]^2 (fp32) ----------------
__global__ void csq_kernel(const float* __restrict__ C, float* __restrict__ csq) {
    int wid  = (blockIdx.x * blockDim.x + threadIdx.x) >> 6;   // one wave per k
    int lane = threadIdx.x & 63;
    const float4* p = (const float4*)(C + (size_t)wid * DIM);
    float4 a = p[lane * 2];
    float4 b = p[lane * 2 + 1];
    float s = a.x*a.x + a.y*a.y + a.z*a.z + a.w*a.w
            + b.x*b.x + b.y*b.y + b.z*b.z + b.w*b.w;
    #pragma unroll
    for (int m = 1; m < 64; m <<= 1) s += __shfl_xor(s, m, 64);
    if (lane == 0) csq[wid] = s;
}

// ---------------- one-shot fp32 -> bf16 hi/lo split ----------------
__global__ void split_kernel(const float* __restrict__ src,
                             unsigned short* __restrict__ h,
                             unsigned short* __restrict__ l, int n4) {
    int stride = gridDim.x * 256;
    for (int i = blockIdx.x * 256 + threadIdx.x; i < n4; i += stride) {
        float4 v = ((const float4*)src)[i];
        ushort4 hh, ll;
        float f;
        f = v.x; hh.x = f2bf_rn(f); ll.x = f2bf_rn(f - bf2f(hh.x));
        f = v.y; hh.y = f2bf_rn(f); ll.y = f2bf_rn(f - bf2f(hh.y));
        f = v.z; hh.z = f2bf_rn(f); ll.z = f2bf_rn(f - bf2f(hh.z));
        f = v.w; hh.w = f2bf_rn(f); ll.w = f2bf_rn(f - bf2f(hh.w));
        ((ushort4*)h)[i] = hh;
        ((ushort4*)l)[i] = ll;
    }
}

// ---------------- fused GEMM + argmin, counted-vmcnt pipeline --------------
// LDS per buffer: Ah[0,8192) Al[8192,16384) Bh[16384,24576) Bl[24576,32768),
// each array [row][group 0..3][8 elems]; LDS[row][g] holds GLOBAL k-group
// g ^ ((row>>1)&3) (swizzle on the per-lane global source address; linear
// LDS dest as global_load_lds requires). Fragment reads use the same XOR
// (verified 0 conflicts, r2-r4).
// Per-thread issue order per tile (8 gloads): p0:[AhA1,AlA1,ChB0]
// p1:[ChB1,ClB0,ClB1] p2:[AhA2,AlA2]. h1 = first 6 (A rows {0-63,128-191}
// + all B), h2 = last 2 (A rows {64-127,192-255}).
__global__ __launch_bounds__(512, 2)
void gemm_argmin(const unsigned short* __restrict__ Xh,
                 const unsigned short* __restrict__ Xl,
                 const unsigned short* __restrict__ Ch,
                 const unsigned short* __restrict__ Cl,
                 const float* __restrict__ csq,
                 unsigned long long* __restrict__ packed) {
    extern __shared__ unsigned short smem[];   // 2 * LDSBUF elements (128 KB)

    // XCD-aware mapping: the 4 col-tiles of one row-tile run concurrently
    // on one XCD -> X tile (512 KB) fetched into that L2 once.
    int b  = blockIdx.x;
    int x  = b & 7;
    int m8 = b >> 3;                   // 0..127
    int rowtile = x * 32 + (m8 >> 2);  // 0..255
    int coltile = m8 & 3;              // 0..3
    int n0 = rowtile * 256;
    int k0 = coltile * 256;

    int tid  = threadIdx.x;
    int w    = tid >> 6;
    int lane = tid & 63;
    int wr   = w >> 2, wc = w & 3;     // 2M x 4N waves; wave tile 128x64
    int rbase = wr * 128, cbase = wc * 64;
    int lrow = lane & 15;
    int lk   = lane >> 4;              // 0..3
    int sg   = lk ^ ((lrow >> 1) & 3); // swizzled k-group for frag reads

    // staging invariants: thread -> (srow = tid>>2, sgrp = tid&3)
    int srow = tid >> 2;               // 0..127
    int sgrp = tid & 3;
    int r1   = (srow < 64) ? srow : srow + 64;     // A-h1 row
    int ggA  = sgrp ^ ((r1 >> 1) & 3);             // same for r1 and r1+64
    int gB   = sgrp ^ ((srow >> 1) & 3);           // same for srow and srow+128
    size_t oA1 = (size_t)(n0 + r1) * DIM + ggA * 8;
    size_t oA2 = oA1 + (size_t)64 * DIM;
    size_t oB0 = (size_t)(k0 + srow) * DIM + gB * 8;
    size_t oB1 = oB0 + (size_t)128 * DIM;
    // wave-uniform LDS dest offsets (HW adds lane*16B)
    int rowA1_0 = (w < 4) ? w * 16 : w * 16 + 64;
    int dA1  = rowA1_0 * 32;
    int dA2  = dA1 + 2048;             // +64 rows
    int dB0  = 16384 + w * 512;        // B rows w*16..
    int dB1  = dB0 + 4096;             // +128 rows
    int dBl0 = dB0 + 8192;
    int dBl1 = dB1 + 8192;

    f32x4 acc[8][4];
    #pragma unroll
    for (int i = 0; i < 8; i++)
        #pragma unroll
        for (int j = 0; j < 4; j++)
            acc[i][j] = (f32x4){0.f, 0.f, 0.f, 0.f};

    bf16x8 bh[4], bl[4], ah[2], al[2];

    auto mfma_phase = [&](int mb) {
        __builtin_amdgcn_s_setprio(1);
        // pass-major: 8 independent MFMAs between dependent acc reuses
        #pragma unroll
        for (int mm = 0; mm < 2; mm++)
            #pragma unroll
            for (int n = 0; n < 4; n++)
                acc[mb + mm][n] = __builtin_amdgcn_mfma_f32_16x16x32_bf16(ah[mm], bh[n], acc[mb + mm][n], 0, 0, 0);
        #pragma unroll
        for (int mm = 0; mm < 2; mm++)
            #pragma unroll
            for (int n = 0; n < 4; n++)
                acc[mb + mm][n] = __builtin_amdgcn_mfma_f32_16x16x32_bf16(ah[mm], bl[n], acc[mb + mm][n], 0, 0, 0);
        #pragma unroll
        for (int mm = 0; mm < 2; mm++)
            #pragma unroll
            for (int n = 0; n < 4; n++)
                acc[mb + mm][n] = __builtin_amdgcn_mfma_f32_16x16x32_bf16(al[mm], bh[n], acc[mb + mm][n], 0, 0, 0);
        __builtin_amdgcn_s_setprio(0);
    };

    // prologue: tile 0, canonical issue order (h1 first 6, h2 last 2)
    {
        unsigned short* b0 = smem;
        gload16(Xh + oA1, b0 + dA1);
        gload16(Xl + oA1, b0 + 8192 + dA1);
        gload16(Ch + oB0, b0 + dB0);
        gload16(Ch + oB1, b0 + dB1);
        gload16(Cl + oB0, b0 + dBl0);
        gload16(Cl + oB1, b0 + dBl1);
        gload16(Xh + oA2, b0 + dA2);
        gload16(Xl + oA2, b0 + 8192 + dA2);
    }

    for (int t = 0; t < NT; ++t) {
        // top: h1(t) done (issued >=4 phases ago); h2(t) may still fly
        asm volatile("s_waitcnt vmcnt(2)" ::: "memory");
        __builtin_amdgcn_s_barrier();
        asm volatile("" ::: "memory");

        const unsigned short* buf = smem + (t & 1) * LDSBUF;
        const unsigned short* pA = buf + (rbase + lrow) * 32 + sg * 8;
        const unsigned short* pB = buf + 16384 + (cbase + lrow) * 32 + sg * 8;
        unsigned short* nbuf = smem + ((t + 1) & 1) * LDSBUF;
        size_t dnx = (size_t)(t + 1) * 32;
        bool pre = (t + 1 < NT);

        // ---- p0: B frags (whole tile) + A m0,m1; issue h1a(t+1) ----
        #pragma unroll
        for (int n = 0; n < 4; n++) {
            bh[n] = *(const bf16x8*)(pB + n * 512);
            bl[n] = *(const bf16x8*)(pB + 8192 + n * 512);
        }
        ah[0] = *(const bf16x8*)(pA);
        ah[1] = *(const bf16x8*)(pA + 512);
        al[0] = *(const bf16x8*)(pA + 8192);
        al[1] = *(const bf16x8*)(pA + 8192 + 512);
        if (pre) {
            gload16(Xh + oA1 + dnx, nbuf + dA1);
            gload16(Xl + oA1 + dnx, nbuf + 8192 + dA1);
            gload16(Ch + oB0 + dnx, nbuf + dB0);
        }
        mfma_phase(0);

        // ---- p1: A m2,m3; issue h1b(t+1) ----
        ah[0] = *(const bf16x8*)(pA + 2 * 512);
        ah[1] = *(const bf16x8*)(pA + 3 * 512);
        al[0] = *(const bf16x8*)(pA + 8192 + 2 * 512);
        al[1] = *(const bf16x8*)(pA + 8192 + 3 * 512);
        if (pre) {
            gload16(Ch + oB1 + dnx, nbuf + dB1);
            gload16(Cl + oB0 + dnx, nbuf + dBl0);
            gload16(Cl + oB1 + dnx, nbuf + dBl1);
        }
        mfma_phase(2);

        // mid: h2(t) done (issued last tile); h1(t+1)'s 6 stay in flight
        if (pre) asm volatile("s_waitcnt vmcnt(6)" ::: "memory");
        else     asm volatile("s_waitcnt vmcnt(0)" ::: "memory");
        __builtin_amdgcn_s_barrier();
        asm volatile("" ::: "memory");

        // ---- p2: A m4,m5; issue h2(t+1) ----
        ah[0] = *(const bf16x8*)(pA + 4 * 512);
        ah[1] = *(const bf16x8*)(pA + 5 * 512);
        al[0] = *(const bf16x8*)(pA + 8192 + 4 * 512);
        al[1] = *(const bf16x8*)(pA + 8192 + 5 * 512);
        if (pre) {
            gload16(Xh + oA2 + dnx, nbuf + dA2);
            gload16(Xl + oA2 + dnx, nbuf + 8192 + dA2);
        }
        mfma_phase(4);

        // ---- p3: A m6,m7 ----
        ah[0] = *(const bf16x8*)(pA + 6 * 512);
        ah[1] = *(const bf16x8*)(pA + 7 * 512);
        al[0] = *(const bf16x8*)(pA + 8192 + 6 * 512);
        al[1] = *(const bf16x8*)(pA + 8192 + 7 * 512);
        mfma_phase(6);
    }

    // Epilogue: score = csq[col] - 2*cross; per-row packed-min, atomic merge.
    float cs[4];
    #pragma unroll
    for (int n = 0; n < 4; n++) cs[n] = csq[k0 + cbase + n * 16 + lrow];

    #pragma unroll
    for (int m = 0; m < 8; m++) {
        #pragma unroll
        for (int r = 0; r < 4; r++) {
            unsigned long long best = ~0ull;
            #pragma unroll
            for (int n = 0; n < 4; n++) {
                float s = cs[n] - 2.0f * acc[m][n][r];
                unsigned kb  = __float_as_uint(s);
                unsigned key = kb ^ (unsigned)(((int)kb >> 31) | 0x80000000);
                unsigned col = (unsigned)(k0 + cbase + n * 16 + lrow);
                unsigned long long pk = (((unsigned long long)key) << 32) | col;
                best = pk < best ? pk : best;
            }
            #pragma unroll
            for (int mask = 1; mask <= 8; mask <<= 1) {
                unsigned hi = __shfl_xor((unsigned)(best >> 32), mask, 64);
                unsigned lo = __shfl_xor((unsigned)(best & 0xFFFFFFFFu), mask, 64);
                unsigned long long other = (((unsigned long long)hi) << 32) | lo;
                best = other < best ? other : best;
            }
            if (lrow == 0) {
                int grow = n0 + rbase + m * 16 + lk * 4 + r;
                atomicMin(&packed[grow], best);
            }
        }
    }
}

// ---------------- fallback GEMM (in-kernel conversion, round-1 path) -------
__device__ __forceinline__ void stage_tile_fb(const float* __restrict__ src,
                                              unsigned short* __restrict__ Hh,
                                              unsigned short* __restrict__ Hl,
                                              int t) {
    int rsub = t >> 4;
    int f4i  = t & 15;
    int g    = f4i >> 1;
    int off  = (f4i & 1) * 4;
    #pragma unroll
    for (int p = 0; p < 8; p++) {
        int row = p * 16 + rsub;
        float4 v = *(const float4*)(src + (size_t)row * DIM + f4i * 4);
        ushort4 h, l;
        float f;
        f = v.x; h.x = f2bf_rn(f); l.x = f2bf_rn(f - bf2f(h.x));
        f = v.y; h.y = f2bf_rn(f); l.y = f2bf_rn(f - bf2f(h.y));
        f = v.z; h.z = f2bf_rn(f); l.z = f2bf_rn(f - bf2f(h.z));
        f = v.w; h.w = f2bf_rn(f); l.w = f2bf_rn(f - bf2f(h.w));
        int sg  = g ^ (row & 7);
        int idx = row * 64 + sg * 8 + off;
        *(ushort4*)(Hh + idx) = h;
        *(ushort4*)(Hl + idx) = l;
    }
}

__global__ __launch_bounds__(256, 2)
void gemm_argmin_fb(const float* __restrict__ X, const float* __restrict__ C,
                    const float* __restrict__ csq,
                    unsigned long long* __restrict__ packed) {
    __shared__ unsigned short AhL[128 * 64];
    __shared__ unsigned short AlL[128 * 64];
    __shared__ unsigned short BhL[128 * 64];
    __shared__ unsigned short BlL[128 * 64];

    int b = blockIdx.x;
    int x = b & 7;
    int m8 = b >> 3;
    int rowtile = x * 64 + (m8 >> 3);
    int coltile = m8 & 7;
    int n0 = rowtile * 128;
    int k0 = coltile * 128;

    int t    = threadIdx.x;
    int w    = t >> 6;
    int lane = t & 63;
    int wr   = w >> 1, wc = w & 1;
    int rbase = wr * 64, cbase = wc * 64;
    int lrow = lane & 15;
    int lk   = lane >> 4;

    f32x4 acc[4][4];
    #pragma unroll
    for (int i = 0; i < 4; i++)
        #pragma unroll
        for (int j = 0; j < 4; j++)
            acc[i][j] = (f32x4){0.f, 0.f, 0.f, 0.f};

    for (int d0 = 0; d0 < DIM; d0 += 64) {
        stage_tile_fb(X + (size_t)n0 * DIM + d0, AhL, AlL, t);
        stage_tile_fb(C + (size_t)k0 * DIM + d0, BhL, BlL, t);
        __syncthreads();

        #pragma unroll
        for (int kk = 0; kk < 2; kk++) {
            int gidx = kk * 4 + lk;
            bf16x8 ah[4], al[4], bh[4], bl[4];
            #pragma unroll
            for (int m = 0; m < 4; m++) {
                int row = rbase + m * 16 + lrow;
                int sg  = gidx ^ (row & 7);
                ah[m] = *(const bf16x8*)&AhL[row * 64 + sg * 8];
                al[m] = *(const bf16x8*)&AlL[row * 64 + sg * 8];
            }
            #pragma unroll
            for (int n = 0; n < 4; n++) {
                int col = cbase + n * 16 + lrow;
                int sg  = gidx ^ (col & 7);
                bh[n] = *(const bf16x8*)&BhL[col * 64 + sg * 8];
                bl[n] = *(const bf16x8*)&BlL[col * 64 + sg * 8];
            }
            #pragma unroll
            for (int m = 0; m < 4; m++)
                #pragma unroll
                for (int n = 0; n < 4; n++) {
                    acc[m][n] = __builtin_amdgcn_mfma_f32_16x16x32_bf16(ah[m], bh[n], acc[m][n], 0, 0, 0);
                    acc[m][n] = __builtin_amdgcn_mfma_f32_16x16x32_bf16(ah[m], bl[n], acc[m][n], 0, 0, 0);
                    acc[m][n] = __builtin_amdgcn_mfma_f32_16x16x32_bf16(al[m], bh[n], acc[m][n], 0, 0, 0);
                }
        }
        __syncthreads();
    }

    float cs[4];
    #pragma unroll
    for (int n = 0; n < 4; n++) cs[n] = csq[k0 + cbase + n * 16 + lrow];

    #pragma unroll
    for (int m = 0; m < 4; m++) {
        #pragma unroll
        for (int r = 0; r < 4; r++) {
            unsigned long long best = ~0ull;
            #pragma unroll
            for (int n = 0; n < 4; n++) {
                float s = cs[n] - 2.0f * acc[m][n][r];
                unsigned kb  = __float_as_uint(s);
                unsigned key = kb ^ (unsigned)(((int)kb >> 31) | 0x80000000);
                unsigned col = (unsigned)(k0 + cbase + n * 16 + lrow);
                unsigned long long pk = (((unsigned long long)key) << 32) | col;
                best = pk < best ? pk : best;
            }
            #pragma unroll
            for (int mask = 1; mask <= 8; mask <<= 1) {
                unsigned hi = __shfl_xor((unsigned)(best >> 32), mask, 64);
                unsigned lo = __shfl_xor((unsigned)(best & 0xFFFFFFFFu), mask, 64);
                unsigned long long other = (((unsigned long long)hi) << 32) | lo;
                best = other < best ? other : best;
            }
            if (lrow == 0) {
                int grow = n0 + rbase + m * 16 + lk * 4 + r;
                atomicMin(&packed[grow], best);
            }
        }
    }
}

// ---------------- winner -> class ----------------
__global__ void map_kernel(const unsigned long long* __restrict__ packed,
                           const int* __restrict__ classes,
                           int* __restrict__ out) {
    int n = blockIdx.x * 256 + threadIdx.x;
    if (n < N_ROWS) {
        unsigned col = (unsigned)(packed[n] & 0xFFFFFFFFull);
        out[n] = classes[col];
    }
}

extern "C" void kernel_launch(void* const* d_in, const int* in_sizes, int n_in,
                              void* d_out, int out_size, void* d_ws, size_t ws_size,
                              hipStream_t stream) {
    const float* X       = (const float*)d_in[0];
    const float* C       = (const float*)d_in[1];
    const int*   classes = (const int*)d_in[2];
    int*         out     = (int*)d_out;

    char* ws = (char*)d_ws;
    size_t off = 0;
    unsigned long long* packed = (unsigned long long*)(ws + off); off += (size_t)N_ROWS * 8;
    float* csq = (float*)(ws + off);                              off += (size_t)K_CB * 4;
    unsigned short* Xh = (unsigned short*)(ws + off);             off += (size_t)N_ROWS * DIM * 2;
    unsigned short* Xl = (unsigned short*)(ws + off);             off += (size_t)N_ROWS * DIM * 2;
    unsigned short* Ch = (unsigned short*)(ws + off);             off += (size_t)K_CB * DIM * 2;
    unsigned short* Cl = (unsigned short*)(ws + off);             off += (size_t)K_CB * DIM * 2;

    init_kernel<<<N_ROWS / 256, 256, 0, stream>>>(packed);
    csq_kernel<<<K_CB / 4, 256, 0, stream>>>(C, csq);

    if (ws_size >= off) {
        split_kernel<<<2048, 256, 0, stream>>>(X, Xh, Xl, N_ROWS * DIM / 4);
        split_kernel<<<512, 256, 0, stream>>>(C, Ch, Cl, K_CB * DIM / 4);
        hipFuncSetAttribute((const void*)gemm_argmin,
                            hipFuncAttributeMaxDynamicSharedMemorySize,
                            2 * LDSBUF * sizeof(unsigned short));
        gemm_argmin<<<(N_ROWS / 256) * (K_CB / 256), 512,
                      2 * LDSBUF * sizeof(unsigned short), stream>>>(
            Xh, Xl, Ch, Cl, csq, packed);
    } else {
        gemm_argmin_fb<<<(N_ROWS / 128) * (K_CB / 128), 256, 0, stream>>>(X, C, csq, packed);
    }
    map_kernel<<<N_ROWS / 256, 256, 0, stream>>>(packed, classes, out);
}